// Round 9
// baseline (71.261 us; speedup 1.0000x reference)
//
#include <hip/hip_runtime.h>

// DetectionLayer (YOLO head decode), fp32.
// x:   (B=32, C=255, G=76, G=76)  where C = a*85 + k, k in [0,85)
// out: (B, 3*76*76, 85)
// Per (b,a): transpose 85 x 5776 -> 5776 x 85 with per-k elementwise math.
//   k=0: (sigmoid(v)+gx)*stride      k=1: (sigmoid(v)+gy)*stride
//   k=2: exp(v)*anchors[a].w         k=3: exp(v)*anchors[a].h   (stride cancels)
//   k>=4: sigmoid(v)
//
// R9 = R8 with the edge-tile bug fixed (first k-group is all 64 lanes, not
// lane<21). Full-tile path unchanged: 16 cells/wave, wave-private LDS
// (21.76 KB/block, 7 blocks/CU), no barrier, explicit MLP (6 global loads
// hoisted to regs, 6 ds_reads hoisted before 6 NT stores), decode
// specialized so only it=0 sees k<16.

#define GDIM   76
#define GG     5776      // 76*76
#define NC     85        // 80 classes + 5
#define NA     3
#define NCH    255       // NA*NC
#define NCELLS 17328     // NA*GG
#define STRIDEF 8.0f     // 608/76
#define TC     64        // cells per block-tile (4 waves x 16)
#define NTILE  91        // 90 full + 1 edge tile of 16 cells (4 waves x 4)

typedef float f32x4 __attribute__((ext_vector_type(4)));

__device__ __forceinline__ float sigf(float v) {
    return 1.0f / (1.0f + __expf(-v));
}

__device__ __forceinline__ float decode(float val, int k, int s, float aw, float ah) {
    if (k == 0)      return (sigf(val) + (float)(s % GDIM)) * STRIDEF;
    else if (k == 1) return (sigf(val) + (float)(s / GDIM)) * STRIDEF;
    else if (k == 2) return __expf(val) * aw;
    else if (k == 3) return __expf(val) * ah;
    else             return sigf(val);
}

__global__ __launch_bounds__(256)
void det_decode_kernel(const float* __restrict__ x,
                       const float* __restrict__ anchors,
                       float* __restrict__ out) {
    __shared__ float lds[4][16 * NC];   // per-wave private [cell][k], 5440 B each

    const int wave = threadIdx.x >> 6;
    const int lane = threadIdx.x & 63;

    const int blk  = blockIdx.x;
    const int tile = blk % NTILE;
    const int ba   = blk / NTILE;
    const int a    = ba % NA;
    const int b    = ba / NA;

    const int s0   = tile * TC;
    const bool full = (GG - s0 >= TC);          // 90 full tiles, 1 edge (16 cells)

    const float aw = anchors[2 * a];
    const float ah = anchors[2 * a + 1];

    float* __restrict__ ldsw = lds[wave];

    if (full) {
        const int ws0 = s0 + wave * 16;         // this wave's 16 cells
        const float* __restrict__ srcw = x + (size_t)(b * NCH + a * NC) * GG + ws0;
        float* __restrict__ dstw = out + (size_t)(b * NCELLS + a * GG + ws0) * NC;

        // ---- Phase 1a: issue ALL global loads (6 in flight per wave). ----
        // 85 k-rows x 4 quads = 340 float4; e = lane + 64*it, k = e>>2,
        // cell = (e&3)*4: per instr the wave covers 16 k-rows x 64B aligned.
        f32x4 v[6];
        #pragma unroll
        for (int it = 0; it < 5; ++it) {
            const int e    = lane + 64 * it;    // < 320 < 340: all lanes active
            const int k    = e >> 2;
            const int cell = (e & 3) * 4;
            v[it] = *reinterpret_cast<const f32x4*>(srcw + (size_t)k * GG + cell);
        }
        if (lane < 20) {                        // e = 320..339
            const int e    = lane + 320;
            const int k    = e >> 2;
            const int cell = (e & 3) * 4;
            v[5] = *reinterpret_cast<const f32x4*>(srcw + (size_t)k * GG + cell);
        }

        // ---- Phase 1b: decode + LDS scatter. it=0 is the only mixed-k
        // iteration (k=0..15); it>=1 has k>=16 -> pure sigmoid, no branches.
        {
            const int k    = lane >> 2;
            const int cell = (lane & 3) * 4;
            #pragma unroll
            for (int j = 0; j < 4; ++j)
                ldsw[(cell + j) * NC + k] = decode(v[0][j], k, ws0 + cell + j, aw, ah);
        }
        #pragma unroll
        for (int it = 1; it < 5; ++it) {
            const int e    = lane + 64 * it;
            const int k    = e >> 2;            // >= 16
            const int cell = (e & 3) * 4;
            #pragma unroll
            for (int j = 0; j < 4; ++j)
                ldsw[(cell + j) * NC + k] = sigf(v[it][j]);
        }
        if (lane < 20) {
            const int e    = lane + 320;
            const int k    = e >> 2;            // >= 80
            const int cell = (e & 3) * 4;
            #pragma unroll
            for (int j = 0; j < 4; ++j)
                ldsw[(cell + j) * NC + k] = sigf(v[5][j]);
        }

        // ---- Phase 2: hoist 6 ds_read_b128, then 6 NT stores. ----
        // Wave's output span = 16*85 = 1360 contiguous floats = 340 float4,
        // same linear order as LDS. Same-wave dependency only, no barrier.
        f32x4 w[6];
        #pragma unroll
        for (int it = 0; it < 5; ++it)
            w[it] = *reinterpret_cast<const f32x4*>(ldsw + 4 * (lane + 64 * it));
        if (lane < 20)
            w[5] = *reinterpret_cast<const f32x4*>(ldsw + 4 * (lane + 320));

        #pragma unroll
        for (int it = 0; it < 5; ++it)
            __builtin_nontemporal_store(w[it],
                reinterpret_cast<f32x4*>(dstw + 4 * (lane + 64 * it)));
        if (lane < 20)
            __builtin_nontemporal_store(w[5],
                reinterpret_cast<f32x4*>(dstw + 4 * (lane + 320)));
    } else {
        // Edge tile: 16 cells total, 4 cells per wave. Per k-row one float4.
        // Group 0: k = lane (0..63, ALL lanes). Group 1: k = lane+64 (<85).
        const int ws0 = s0 + wave * 4;
        const float* __restrict__ srcw = x + (size_t)(b * NCH + a * NC) * GG + ws0;
        float* __restrict__ dstw = out + (size_t)(b * NCELLS + a * GG + ws0) * NC;

        f32x4 v0, v1;
        v0 = *reinterpret_cast<const f32x4*>(srcw + (size_t)lane * GG);
        if (lane < NC - 64)                     // lanes 0..20, k = 64..84
            v1 = *reinterpret_cast<const f32x4*>(srcw + (size_t)(lane + 64) * GG);

        {
            const int k = lane;                 // 0..63
            #pragma unroll
            for (int j = 0; j < 4; ++j)
                ldsw[j * NC + k] = decode(v0[j], k, ws0 + j, aw, ah);
        }
        if (lane < NC - 64) {
            const int k = lane + 64;            // 64..84, pure sigmoid
            #pragma unroll
            for (int j = 0; j < 4; ++j)
                ldsw[j * NC + k] = sigf(v1[j]);
        }

        // Output span = 4*85 = 340 floats = 85 float4.
        f32x4 w0, w1;
        w0 = *reinterpret_cast<const f32x4*>(ldsw + 4 * lane);
        if (lane < 21)
            w1 = *reinterpret_cast<const f32x4*>(ldsw + 4 * (lane + 64));
        __builtin_nontemporal_store(w0, reinterpret_cast<f32x4*>(dstw + 4 * lane));
        if (lane < 21)
            __builtin_nontemporal_store(w1,
                reinterpret_cast<f32x4*>(dstw + 4 * (lane + 64)));
    }
}

extern "C" void kernel_launch(void* const* d_in, const int* in_sizes, int n_in,
                              void* d_out, int out_size, void* d_ws, size_t ws_size,
                              hipStream_t stream) {
    const float* x       = (const float*)d_in[0];
    const float* anchors = (const float*)d_in[1];
    float* out           = (float*)d_out;

    const int B = 32;
    const int nblocks = B * NA * NTILE;   // 32*3*91 = 8736
    det_decode_kernel<<<dim3(nblocks), dim3(256), 0, stream>>>(x, anchors, out);
}

// Round 10
// 62.557 us; speedup vs baseline: 1.1391x; 1.1391x over previous
//
#include <hip/hip_runtime.h>

// DetectionLayer (YOLO head decode), fp32.
// x:   (B=32, C=255, G=76, G=76)  where C = a*85 + k, k in [0,85)
// out: (B, 3*76*76, 85)
// Per (b,a): transpose 85 x 5776 -> 5776 x 85 with per-k elementwise math.
//   k=0: (sigmoid(v)+gx)*stride      k=1: (sigmoid(v)+gy)*stride
//   k=2: exp(v)*anchors[a].w         k=3: exp(v)*anchors[a].h   (stride cancels)
//   k>=4: sigmoid(v)
//
// R10 = R4 (best, 66.7us) + XCD-aware bijective block swizzle (T1).
// 8736 blocks % 8 XCDs == 0; logical = (hw%8)*1092 + hw/8 -> each XCD owns
// 1092 consecutive tiles = exactly 12 complete (b,a) planes, so the 64B-
// aligned row-chunk line straddles and k-row walks stay in one XCD's L2.
// R9 lesson: explicit load/ds hoisting regressed (compiler already schedules
// MLP); keep the simple loop form.

#define GDIM   76
#define GG     5776      // 76*76
#define NC     85        // 80 classes + 5
#define NA     3
#define NCH    255       // NA*NC
#define NCELLS 17328     // NA*GG
#define STRIDEF 8.0f     // 608/76
#define TC     64        // cells per block-tile (4 waves x 16)
#define NTILE  91        // 90 full + 1 edge tile of 16 cells (4 waves x 4)
#define NBLK   (32 * NA * NTILE)   // 8736
#define CPX    (NBLK / 8)          // 1092 blocks per XCD

typedef float f32x4 __attribute__((ext_vector_type(4)));

__device__ __forceinline__ float sigf(float v) {
    return 1.0f / (1.0f + __expf(-v));
}

__device__ __forceinline__ float decode(float val, int k, int s, float aw, float ah) {
    if (k == 0)      return (sigf(val) + (float)(s % GDIM)) * STRIDEF;
    else if (k == 1) return (sigf(val) + (float)(s / GDIM)) * STRIDEF;
    else if (k == 2) return __expf(val) * aw;
    else if (k == 3) return __expf(val) * ah;
    else             return sigf(val);
}

__global__ __launch_bounds__(256)
void det_decode_kernel(const float* __restrict__ x,
                       const float* __restrict__ anchors,
                       float* __restrict__ out) {
    __shared__ float lds[4][16 * NC];   // per-wave private [cell][k]

    const int wave = threadIdx.x >> 6;
    const int lane = threadIdx.x & 63;

    // XCD-aware bijective swizzle: hw blockIdx round-robins XCDs (hw%8);
    // give XCD x the contiguous logical range [x*CPX, (x+1)*CPX).
    const int hw   = blockIdx.x;
    const int blk  = (hw & 7) * CPX + (hw >> 3);

    const int tile = blk % NTILE;
    const int ba   = blk / NTILE;
    const int a    = ba % NA;
    const int b    = ba / NA;

    const int s0   = tile * TC;
    const bool full = (GG - s0 >= TC);          // 90 full tiles, 1 edge (16 cells)

    const float aw = anchors[2 * a];
    const float ah = anchors[2 * a + 1];

    float* __restrict__ ldsw = lds[wave];

    if (full) {
        const int ws0 = s0 + wave * 16;         // this wave's 16 cells
        const float* __restrict__ srcw = x + (size_t)(b * NCH + a * NC) * GG + ws0;
        float* __restrict__ dstw = out + (size_t)(b * NCELLS + a * GG + ws0) * NC;

        // Phase 1: 85 k-rows x 4 quads = 340 float4 loads; per instr the wave
        // covers 16 k-rows x 256B contiguous. Scatter to lds[cell][k].
        #pragma unroll
        for (int it = 0; it < 6; ++it) {
            const int e = lane + 64 * it;
            if (e < NC * 4) {
                const int k    = e >> 2;
                const int cell = (e & 3) * 4;
                const f32x4 v = *reinterpret_cast<const f32x4*>(srcw + (size_t)k * GG + cell);
                #pragma unroll
                for (int j = 0; j < 4; ++j)
                    ldsw[(cell + j) * NC + k] = decode(v[j], k, ws0 + cell + j, aw, ah);
            }
        }

        // Phase 2: wave's output span = 16*85 = 1360 contiguous floats, same
        // linear order as LDS. No barrier needed (same-wave dependency).
        #pragma unroll
        for (int it = 0; it < 6; ++it) {
            const int e = lane + 64 * it;
            if (e < 340) {
                const f32x4 v = *reinterpret_cast<const f32x4*>(ldsw + 4 * e);
                __builtin_nontemporal_store(v, reinterpret_cast<f32x4*>(dstw + 4 * e));
            }
        }
    } else {
        const int ws0 = s0 + wave * 4;          // edge: 4 cells per wave
        const float* __restrict__ srcw = x + (size_t)(b * NCH + a * NC) * GG + ws0;
        float* __restrict__ dstw = out + (size_t)(b * NCELLS + a * GG + ws0) * NC;

        #pragma unroll
        for (int it = 0; it < 2; ++it) {
            const int k = lane + 64 * it;       // one quad per k-row
            if (k < NC) {
                const f32x4 v = *reinterpret_cast<const f32x4*>(srcw + (size_t)k * GG);
                #pragma unroll
                for (int j = 0; j < 4; ++j)
                    ldsw[j * NC + k] = decode(v[j], k, ws0 + j, aw, ah);
            }
        }
        #pragma unroll
        for (int it = 0; it < 2; ++it) {
            const int e = lane + 64 * it;       // 4*85 = 340 floats = 85 float4
            if (e < NC) {
                const f32x4 v = *reinterpret_cast<const f32x4*>(ldsw + 4 * e);
                __builtin_nontemporal_store(v, reinterpret_cast<f32x4*>(dstw + 4 * e));
            }
        }
    }
}

extern "C" void kernel_launch(void* const* d_in, const int* in_sizes, int n_in,
                              void* d_out, int out_size, void* d_ws, size_t ws_size,
                              hipStream_t stream) {
    const float* x       = (const float*)d_in[0];
    const float* anchors = (const float*)d_in[1];
    float* out           = (float*)d_out;

    det_decode_kernel<<<dim3(NBLK), dim3(256), 0, stream>>>(x, anchors, out);
}